// Round 3
// baseline (247.068 us; speedup 1.0000x reference)
//
#include <hip/hip_runtime.h>

#define DIMN 32
#define HD   32
#define FN   16
#define FE   8
#define NG   64
#define CAP  64   // bucket capacity (in-degree ~Poisson(16); overflow fallback below)
#define NPW  4    // nodes per wave in K3

// K1: out = relu(x @ lin0_w^T + lin0_b); zero deg/aggfb/u/done.
__global__ __launch_bounds__(256) void k1_out(
    const float* __restrict__ x, const float* __restrict__ lin0_w,
    const float* __restrict__ lin0_b,
    float* __restrict__ outn, float* __restrict__ aggfb, float* __restrict__ u,
    int* __restrict__ deg, int* __restrict__ done, int N)
{
    const int gt = blockIdx.x * 256 + threadIdx.x;
    if (gt >= N * DIMN) return;
    const int n = gt >> 5, d = gt & 31;

    float s = lin0_b[d];
    const float* xr = x + (size_t)n * FN;
    const float* wr = lin0_w + d * FN;
    #pragma unroll
    for (int j = 0; j < FN; ++j) s = fmaf(xr[j], wr[j], s);
    outn[gt] = fmaxf(s, 0.f);

    aggfb[gt] = 0.f;
    if (d == 0) deg[n] = 0;
    if (gt < NG * HD) u[gt] = 0.f;
    if (gt == 0) *done = 0;
}

// Kb: bucket edges by destination. eidx[dst*CAP + pos] = e.
// Overflow (statistically never: max in-degree ~34 for this dataset): compute the
// message directly and atomicAdd into aggfb, which K3 adds before relu.
__global__ __launch_bounds__(256) void kb_bucket(
    const int* __restrict__ ei, const float* __restrict__ ea,
    const float* __restrict__ outn, const float* __restrict__ nn_w,
    const float* __restrict__ nn_b,
    int* __restrict__ deg, int* __restrict__ eidx, float* __restrict__ aggfb, int E)
{
    const int e = blockIdx.x * 256 + threadIdx.x;
    if (e >= E) return;
    const int dst = ei[E + e];
    const int pos = atomicAdd(&deg[dst], 1);
    if (pos < CAP) {
        eidx[dst * CAP + pos] = e;
    } else {
        const int src = ei[e];
        float ef[FE];
        #pragma unroll
        for (int f = 0; f < FE; ++f) ef[f] = ea[(size_t)e * FE + f];
        for (int h = 0; h < HD; ++h) {
            float m = 0.f;
            for (int d = 0; d < DIMN; ++d) {
                float wdh = nn_b[d * HD + h];
                #pragma unroll
                for (int f = 0; f < FE; ++f)
                    wdh = fmaf(ef[f], nn_w[(d * HD + h) * FE + f], wdh);
                m = fmaf(outn[(size_t)src * DIMN + d], wdh, m);
            }
            atomicAdd(aggfb + (size_t)dst * HD + h, m);
        }
    }
}

// K3: per dst node accumulate T[d,f] = sum_e out[src,d]*ea[e,f] in registers
// (lane l owns d = l&31, f in 4p..4p+3, p = l>>5), then contract with nn_w
// staged transposed in LDS (bank = h, conflict-free). nn_b via S[d] = sum_e
// out[src,d]. Root + relu + run-length pool into u. Last block computes head.
__global__ __launch_bounds__(256) void k3_gather(
    const int* __restrict__ ei, const float* __restrict__ ea,
    const float* __restrict__ outn, const float* __restrict__ nn_w,
    const float* __restrict__ nn_b, const float* __restrict__ root_w,
    const float* __restrict__ conv_b,
    const int* __restrict__ deg, const int* __restrict__ eidx,
    const float* __restrict__ aggfb, const int* __restrict__ batch,
    const float* __restrict__ lin1_w, const float* __restrict__ lin1_b,
    const float* __restrict__ lin2_w, const float* __restrict__ lin2_b,
    float* __restrict__ u, int* __restrict__ done, float* __restrict__ outp,
    int N, int nblocks)
{
    __shared__ float s_nnw2[DIMN * FE * HD];  // [(d*8+f)*32 + h]  32 KB
    __shared__ float s_nnb[DIMN * HD];        // [d*32 + h]         4 KB
    __shared__ float s_rw[DIMN * HD];         // [d*32 + h]         4 KB
    __shared__ float s_cb[HD];
    __shared__ int   s_last;

    const int tid = threadIdx.x;
    for (int i = tid; i < DIMN * FE * HD; i += 256) {
        const int d = i >> 8, rem = i & 255, hh = rem >> 3, f = rem & 7;
        s_nnw2[(d * 8 + f) * 32 + hh] = nn_w[i];   // nn_w[i] = nn_w[(d*32+hh)*8+f]
    }
    for (int i = tid; i < DIMN * HD; i += 256) s_nnb[i] = nn_b[i];
    for (int i = tid; i < DIMN * HD; i += 256) s_rw[i]  = root_w[i];
    if (tid < HD) s_cb[tid] = conv_b[tid];
    __syncthreads();

    const int l   = tid & 63;
    const int h   = l & 31;
    const int p   = l >> 5;
    const int P16 = p << 4;
    const int wid = (blockIdx.x * 4) + (tid >> 6);
    const int nbase = wid * NPW;

    float accp  = 0.f;
    int   g_cur = -1;

    for (int i = 0; i < NPW; ++i) {
        const int n = nbase + i;
        if (n >= N) break;

        const int dn = min(deg[n], CAP);

        // preload this node's edge list + srcs (coalesced / gathered once)
        int e_l = 0, s_l = 0;
        if (l < dn) {
            e_l = eidx[n * CAP + l];
            s_l = ei[e_l];
        }

        float T0 = 0.f, T1 = 0.f, T2 = 0.f, T3 = 0.f, S = 0.f;
        for (int j = 0; j < dn; ++j) {
            const int e   = __shfl(e_l, j, 64);
            const int src = __shfl(s_l, j, 64);
            const float4 w4 = *(const float4*)(ea + (size_t)e * FE + 4 * p);
            const float  o  = outn[(size_t)src * DIMN + h];  // out[src, d=l&31]
            S  += o;
            T0 = fmaf(o, w4.x, T0);
            T1 = fmaf(o, w4.y, T1);
            T2 = fmaf(o, w4.z, T2);
            T3 = fmaf(o, w4.w, T3);
        }

        // contract: acc(h) = sum_{d in [P16,P16+16), f} T[d,f]*nnw[d,f,h]
        float acc = 0.f;
        #pragma unroll
        for (int dd = 0; dd < 16; ++dd) {
            const int d    = P16 + dd;
            const int base = d * 256 + h;            // (d*8+0)*32 + h
            acc = fmaf(__shfl(T0, d,      64), s_nnw2[base + 0 * 32], acc);
            acc = fmaf(__shfl(T1, d,      64), s_nnw2[base + 1 * 32], acc);
            acc = fmaf(__shfl(T2, d,      64), s_nnw2[base + 2 * 32], acc);
            acc = fmaf(__shfl(T3, d,      64), s_nnw2[base + 3 * 32], acc);
            acc = fmaf(__shfl(T0, 32 + d, 64), s_nnw2[base + 4 * 32], acc);
            acc = fmaf(__shfl(T1, 32 + d, 64), s_nnw2[base + 5 * 32], acc);
            acc = fmaf(__shfl(T2, 32 + d, 64), s_nnw2[base + 6 * 32], acc);
            acc = fmaf(__shfl(T3, 32 + d, 64), s_nnw2[base + 7 * 32], acc);
        }
        // nn_b part: + sum_d S[d] * nn_b[d,h]
        #pragma unroll
        for (int dd = 0; dd < 16; ++dd) {
            const int d = P16 + dd;
            acc = fmaf(__shfl(S, d, 32), s_nnb[d * 32 + h], acc);
        }
        // root part: + sum_d out[n,d] * root_w[d,h]
        const float orow = outn[(size_t)n * DIMN + h];
        #pragma unroll
        for (int dd = 0; dd < 16; ++dd) {
            const int d = P16 + dd;
            acc = fmaf(__shfl(orow, d, 32), s_rw[d * 32 + h], acc);
        }
        acc += __shfl_xor(acc, 32);   // combine the two half-wave partials

        const float v = fmaxf(acc + s_cb[h] + aggfb[(size_t)n * HD + h], 0.f);

        // run-length pool (batch sorted; uniform across wave)
        const int g = batch[n];
        if (g != g_cur) {
            if (g_cur >= 0 && p == 0) atomicAdd(u + (size_t)g_cur * HD + h, accp);
            g_cur = g;
            accp = v;
        } else {
            accp += v;
        }
    }
    if (g_cur >= 0 && p == 0) atomicAdd(u + (size_t)g_cur * HD + h, accp);

    // ---- last-block-done: fuse the head ----
    __threadfence();            // make this block's u atomics globally visible
    __syncthreads();
    if (tid == 0) {
        const int old = atomicAdd(done, 1);
        s_last = (old == nblocks - 1) ? 1 : 0;
    }
    __syncthreads();
    if (s_last && tid < NG) {
        const int g = tid;
        float ur[HD];
        #pragma unroll
        for (int hh = 0; hh < HD; ++hh)
            ur[hh] = atomicAdd(&u[(size_t)g * HD + hh], 0.f);  // coherent read
        float acc2 = lin2_b[0];
        #pragma unroll
        for (int i = 0; i < 16; ++i) {
            float o = lin1_b[i];
            #pragma unroll
            for (int hh = 0; hh < HD; ++hh)
                o = fmaf(ur[hh], lin1_w[i * HD + hh], o);
            o = fmaxf(o, 0.f);
            acc2 = fmaf(o, lin2_w[i], acc2);
        }
        outp[g] = acc2;
    }
}

extern "C" void kernel_launch(void* const* d_in, const int* in_sizes, int n_in,
                              void* d_out, int out_size, void* d_ws, size_t ws_size,
                              hipStream_t stream)
{
    const float* x      = (const float*)d_in[0];
    const int*   ei     = (const int*)  d_in[1];
    const float* ea     = (const float*)d_in[2];
    const int*   batch  = (const int*)  d_in[3];
    const float* lin0_w = (const float*)d_in[4];
    const float* lin0_b = (const float*)d_in[5];
    const float* nn_w   = (const float*)d_in[6];
    const float* nn_b   = (const float*)d_in[7];
    const float* root_w = (const float*)d_in[8];
    const float* conv_b = (const float*)d_in[9];
    const float* lin1_w = (const float*)d_in[10];
    const float* lin1_b = (const float*)d_in[11];
    const float* lin2_w = (const float*)d_in[12];
    const float* lin2_b = (const float*)d_in[13];

    const int N = in_sizes[0] / FN;   // 12500
    const int E = in_sizes[2] / FE;   // 200000

    float* ws    = (float*)d_ws;
    float* outn  = ws;                           // N*32
    float* aggfb = outn  + (size_t)N * DIMN;     // N*32 (overflow fallback)
    float* u     = aggfb + (size_t)N * DIMN;     // 64*32
    int*   deg   = (int*)(u + (size_t)NG * HD);  // N
    int*   eidx  = deg + N;                      // N*CAP
    int*   done  = eidx + (size_t)N * CAP;       // 1

    const int nb1 = (N * DIMN + 255) / 256;      // 1563
    k1_out<<<nb1, 256, 0, stream>>>(x, lin0_w, lin0_b, outn, aggfb, u, deg, done, N);

    const int nbb = (E + 255) / 256;             // 782
    kb_bucket<<<nbb, 256, 0, stream>>>(ei, ea, outn, nn_w, nn_b, deg, eidx, aggfb, E);

    const int nb3 = (N + NPW * 4 - 1) / (NPW * 4);  // 782 (16 nodes per block)
    k3_gather<<<nb3, 256, 0, stream>>>(ei, ea, outn, nn_w, nn_b, root_w, conv_b,
                                       deg, eidx, aggfb, batch,
                                       lin1_w, lin1_b, lin2_w, lin2_b,
                                       u, done, (float*)d_out, N, nb3);
}